// Round 18
// baseline (291.349 us; speedup 1.0000x reference)
//
#include <hip/hip_runtime.h>

// Branch MLP: B=16384 rows, E=4 experts, 512->1024->1024->512, relu/relu/tanh.
// Bucket rows by expert, pad segments to 128-row tiles w/ duplicate rows,
// 3 bf16-MFMA GEMM passes. Weights pre-transposed bf16 [E][N][K]; x
// pre-gathered to permuted bf16 xp.
// R18 GEMM: BM=128, BK=64, 4 waves. B staged via global_load_lds into LDS
// (2-barrier, chunk-XOR swizzle); A-fragments loaded DIRECTLY global->reg
// (wave-private, k-contiguous 16B chunks) so A escapes the per-step
// vmcnt(0)+barrier lockstep and pipelines under MFMA per-wave. LDS 16KB.
// Bijective chunked XCD swizzle (R15) for L2 locality.
//
// Workspace (86.1 MB):
//   ctrl[64] | tileExpert[160] | tileBase[160] | perm[16896]
//   Wt1 (4.19MB) | Wt2 (8.39MB) | Wt3 (4.19MB) | h1 (34.6MB) | h2 (34.6MB)
//   xp (17.3MB) aliases h2 (xp dead before gemm2 writes h2).

#define B_N   16384
#define DIN   512
#define HID   1024
#define DOUT  512
#define MAXTILES 136

typedef __attribute__((ext_vector_type(8))) short bf16x8;
typedef __attribute__((ext_vector_type(4))) float f32x4;
typedef __attribute__((address_space(3))) unsigned int lds_u32;
typedef const __attribute__((address_space(1))) unsigned int glb_u32;

__device__ __forceinline__ void gll16(const void* g, void* l) {
    __builtin_amdgcn_global_load_lds((glb_u32*)g, (lds_u32*)l, 16, 0, 0);
}

__device__ __forceinline__ unsigned short f2bf(float f) {
    unsigned int u = __float_as_uint(f);
    u += 0x7FFFu + ((u >> 16) & 1u);   // RNE
    return (unsigned short)(u >> 16);
}

__device__ __forceinline__ float fast_tanh(float x) {
    x = fminf(fmaxf(x, -9.0f), 9.0f);
    float t = __builtin_amdgcn_exp2f(x * 2.8853900817779268f);
    return (t - 1.0f) * __builtin_amdgcn_rcpf(t + 1.0f);
}

// One block: histogram cmd, zero cursors, build tile plan.
__global__ void plan_all_k(const int* __restrict__ cmd, int* __restrict__ ctrl,
                           int* __restrict__ tileExpert, int* __restrict__ tileBase) {
    __shared__ int h[4];
    int tid = threadIdx.x;
    if (tid < 4) h[tid] = 0;
    __syncthreads();
    int c0 = 0, c1 = 0, c2 = 0, c3 = 0;
    for (int i = tid; i < B_N; i += 256) {
        int e = cmd[i] & 3;
        c0 += (e == 0); c1 += (e == 1); c2 += (e == 2); c3 += (e == 3);
    }
    atomicAdd(&h[0], c0); atomicAdd(&h[1], c1);
    atomicAdd(&h[2], c2); atomicAdd(&h[3], c3);
    __syncthreads();
    if (tid == 0) {
        int P = 0, nt = 0;
        for (int e = 0; e < 4; ++e) {
            ctrl[e] = h[e];
            ctrl[4 + e] = 0;          // scatter cursors
            ctrl[8 + e] = P;
            int tiles = (h[e] + 127) >> 7;
            for (int t = 0; t < tiles; ++t) {
                tileExpert[nt] = e;
                tileBase[nt] = P + t * 128;
                ++nt;
            }
            P += tiles * 128;
        }
        ctrl[12] = P;                 // total padded rows
        ctrl[13] = nt;                // total tiles
    }
}

// Wave-aggregated scatter: one atomicAdd(popcount) per wave per expert.
__global__ void scatter_k(const int* __restrict__ cmd, int* __restrict__ ctrl,
                          int* __restrict__ perm) {
    int i = blockIdx.x * 256 + threadIdx.x;
    int e = cmd[i] & 3;
    int lane = threadIdx.x & 63;
#pragma unroll
    for (int ee = 0; ee < 4; ++ee) {
        unsigned long long mask = __ballot(e == ee);
        if (e == ee) {
            int leader = __ffsll((unsigned long long)mask) - 1;
            int rank = __popcll(mask & ((1ull << lane) - 1ull));
            int wbase = 0;
            if (lane == leader)
                wbase = atomicAdd(&ctrl[4 + ee], __popcll(mask));
            wbase = __builtin_amdgcn_readfirstlane(wbase);
            perm[ctrl[8 + ee] + wbase + rank] = i;
        }
    }
}

// Fused prep: blocks [0,8192) transpose+convert weights (packed uint writes);
// blocks [8192,12416) gather x -> permuted bf16 xp and fill pad perm entries.
__global__ __launch_bounds__(256) void prep_data_k(
    const float* __restrict__ W1, const float* __restrict__ W2,
    const float* __restrict__ W3, unsigned short* __restrict__ Wt1,
    unsigned short* __restrict__ Wt2, unsigned short* __restrict__ Wt3,
    const float* __restrict__ x, unsigned short* __restrict__ xp,
    int* __restrict__ perm, const int* __restrict__ ctrl)
{
    int b = blockIdx.x;
    if (b < 8192) {
        int e = b >> 11, r = b & 2047;
        const float* W; unsigned short* Wt; int KD, ND, kt, nt;
        if (r < 512)       { W = W1; Wt = Wt1; KD = 512;  ND = 1024; kt = r & 15;           nt = r >> 4; }
        else if (r < 1536) { W = W2; Wt = Wt2; KD = 1024; ND = 1024; kt = (r - 512) & 31;   nt = (r - 512) >> 5; }
        else               { W = W3; Wt = Wt3; KD = 1024; ND = 512;  kt = (r - 1536) & 31;  nt = (r - 1536) >> 5; }
        __shared__ float t[32][33];
        size_t base = (size_t)e * KD * ND;
        int k0 = kt * 32, n0 = nt * 32;
        int tx = threadIdx.x & 31, ty = threadIdx.x >> 5;
#pragma unroll
        for (int s = 0; s < 4; ++s)
            t[ty + s * 8][tx] = W[base + (size_t)(k0 + ty + s * 8) * ND + n0 + tx];
        __syncthreads();
        int tx2 = (threadIdx.x & 15) * 2, ny = threadIdx.x >> 4;
#pragma unroll
        for (int s = 0; s < 2; ++s) {
            int n = ny + s * 16;
            unsigned int v = (unsigned)f2bf(t[tx2][n])
                           | ((unsigned)f2bf(t[tx2 + 1][n]) << 16);
            *(unsigned int*)&Wt[base + (size_t)(n0 + n) * KD + k0 + tx2] = v;
        }
    } else {
        int g = b - 8192;
        int p = g * 4 + (int)(threadIdx.x >> 6);
        if (p >= ctrl[12]) return;
        int lane = threadIdx.x & 63;
        int e = (p >= ctrl[9]) + (p >= ctrl[10]) + (p >= ctrl[11]);
        int segBase = ctrl[8 + e];
        int src;
        if (p < segBase + ctrl[e]) {
            src = perm[p];
        } else {
            src = perm[segBase];              // duplicate a valid same-expert row
            if (lane == 0) perm[p] = src;     // so gemm3 scatter-epilogue is safe
        }
        const float* xr = x + (size_t)src * DIN + lane * 8;
        float4 a = *(const float4*)xr;
        float4 c = *(const float4*)(xr + 4);
        uint4 o;
        o.x = (unsigned)f2bf(a.x) | ((unsigned)f2bf(a.y) << 16);
        o.y = (unsigned)f2bf(a.z) | ((unsigned)f2bf(a.w) << 16);
        o.z = (unsigned)f2bf(c.x) | ((unsigned)f2bf(c.y) << 16);
        o.w = (unsigned)f2bf(c.z) | ((unsigned)f2bf(c.w) << 16);
        *(uint4*)(xp + (size_t)p * DIN + lane * 8) = o;
    }
}

// Grouped GEMM: C = act(A @ Wt[e]^T + b[e]). BM=128, BN template (128 or 64),
// BK=64, 256 thr = 4 waves (2x2 quadrants: wave tile 64 x BN/2).
// B: LDS-staged (gll16, chunk-XOR swizzle, 2 barriers/step).
// A: DIRECT global->reg 16B fragment loads (k-contiguous; wave-private, no
// barrier involvement — compiler pipelines them under the MFMA chain).
// Chunked XCD swizzle: XCD x covers tiles [17x,17x+17) x all panels.
template<int K, int N, int BN, int PN, int ACT, bool SCATTER_OUT>
__global__ __launch_bounds__(256) void gemm_k(
    const unsigned short* __restrict__ A, const unsigned short* __restrict__ Bt,
    const float* __restrict__ bias, void* __restrict__ Outp,
    const int* __restrict__ ctrl, const int* __restrict__ tileExpert,
    const int* __restrict__ tileBase, const int* __restrict__ perm)
{
    constexpr int NI = BN / 32;               // frags per wave along N (4 or 2)
    constexpr int BCALLS = BN / 32;           // B staging calls (32 rows each)
    const int l = (int)blockIdx.x + MAXTILES * (int)blockIdx.y;
    const int swz = (l & 7) * (17 * PN) + (l >> 3);
    const int tile = swz / PN;                // PN pow2 -> shift
    const int panel = swz & (PN - 1);
    if (tile >= ctrl[13]) return;
    const int e = tileExpert[tile];
    const int rowBase = tileBase[tile];
    const int n0 = panel * BN;

    __shared__ unsigned short Bls[BN * 64];   // 16 or 8 KB (A not in LDS)

    const int tid = threadIdx.x;
    const int lane = tid & 63;
    const int w = tid >> 6;
    const int wm = w >> 1, wn = w & 1;
    const int lr = lane & 15, lh = lane >> 4;

    f32x4 acc[4][NI] = {};

    // B staging: thread t -> row tr (within 32-row call-block), chunk-slot tc.
    // Source chunk = tc ^ (tr&7)  (row&7 == tr&7 for every call base).
    const int tr = tid >> 3;                  // 0..31
    const int tc = tid & 7;                   // chunk slot 0..7
    const int cs = (tc ^ (tr & 7)) * 8;       // source ushort offset in row
    const unsigned short* Bs = Bt + ((size_t)e * N + n0 + tr) * K + cs;
    const int ldst = tr * 64 + tc * 8;        // ushort idx; byte == tid*16

    // A direct: per-lane base at its fragment row, k-chunk lh*8.
    const unsigned short* Arow = A + (size_t)(rowBase + wm * 64 + lr) * K + lh * 8;

    constexpr int NK = K / 64;
    for (int kq = 0; kq < NK; ++kq) {
        const int k0 = kq * 64;
        __syncthreads();                      // prior reads of Bls done
#pragma unroll
        for (int j = 0; j < BCALLS; ++j)
            gll16(Bs + (size_t)(j * 32) * K + k0, &Bls[j * 2048 + ldst]);
        // A fragments for this K-step (both kk halves) — wave-private loads,
        // issued before the barrier so they fly during the B drain.
        bf16x8 afr[2][4];
#pragma unroll
        for (int kk = 0; kk < 2; ++kk)
#pragma unroll
            for (int mi = 0; mi < 4; ++mi)
                afr[kk][mi] = *(const bf16x8*)(Arow + (size_t)(mi * 16) * K
                                               + k0 + kk * 32);
        __syncthreads();                      // B landed block-wide
#pragma unroll
        for (int kk = 0; kk < 2; ++kk) {
            const int ksl = ((kk * 4 + lh) ^ (lr & 7)) * 8;   // swizzled read
            bf16x8 bfr[NI];
#pragma unroll
            for (int ni = 0; ni < NI; ++ni)
                bfr[ni] = *(const bf16x8*)&Bls[(wn * (BN / 2) + ni * 16 + lr) * 64 + ksl];
#pragma unroll
            for (int mi = 0; mi < 4; ++mi)
#pragma unroll
                for (int ni = 0; ni < NI; ++ni)
                    acc[mi][ni] = __builtin_amdgcn_mfma_f32_16x16x32_bf16(
                        afr[kk][mi], bfr[ni], acc[mi][ni], 0, 0, 0);
        }
    }

    float bv[NI];
    int colv[NI];
#pragma unroll
    for (int ni = 0; ni < NI; ++ni) {
        colv[ni] = n0 + wn * (BN / 2) + ni * 16 + lr;
        bv[ni] = bias[e * N + colv[ni]];
    }
#pragma unroll
    for (int mi = 0; mi < 4; ++mi) {
#pragma unroll
        for (int r = 0; r < 4; ++r) {
            int rowL = wm * 64 + mi * 16 + lh * 4 + r;   // C/D: row=(lane>>4)*4+reg
            int gRow = rowBase + rowL;
            int orow = SCATTER_OUT ? perm[gRow] : gRow;
#pragma unroll
            for (int ni = 0; ni < NI; ++ni) {
                float v = acc[mi][ni][r] + bv[ni];
                if (ACT == 0) v = fmaxf(v, 0.0f);
                else          v = fast_tanh(v);
                if (SCATTER_OUT)
                    ((float*)Outp)[(size_t)orow * N + colv[ni]] = v;
                else
                    ((unsigned short*)Outp)[(size_t)orow * N + colv[ni]] = f2bf(v);
            }
        }
    }
}

extern "C" void kernel_launch(void* const* d_in, const int* in_sizes, int n_in,
                              void* d_out, int out_size, void* d_ws, size_t ws_size,
                              hipStream_t stream) {
    const float* x  = (const float*)d_in[0];
    const int*   cmd= (const int*)d_in[1];
    const float* W1 = (const float*)d_in[2];
    const float* b1 = (const float*)d_in[3];
    const float* W2 = (const float*)d_in[4];
    const float* b2 = (const float*)d_in[5];
    const float* W3 = (const float*)d_in[6];
    const float* b3 = (const float*)d_in[7];
    float* out = (float*)d_out;

    char* w = (char*)d_ws;
    int* ctrl       = (int*)w;
    int* tileExpert = ctrl + 64;
    int* tileBase   = ctrl + 224;
    int* perm       = ctrl + 512;                         // 16896 ints
    unsigned short* Wt1 = (unsigned short*)(w + 131072);
    unsigned short* Wt2 = (unsigned short*)(w + 131072 + 4194304);
    unsigned short* Wt3 = (unsigned short*)(w + 131072 + 12582912);
    unsigned short* h1  = (unsigned short*)(w + 131072 + 16777216);
    unsigned short* h2  = h1 + (size_t)16896 * HID;       // 34.6 MB each
    unsigned short* xp  = h2;                             // aliases h2 (WAR-safe)

    plan_all_k<<<1, 256, 0, stream>>>(cmd, ctrl, tileExpert, tileBase);
    scatter_k<<<B_N / 256, 256, 0, stream>>>(cmd, ctrl, perm);
    prep_data_k<<<8192 + 4224, 256, 0, stream>>>(W1, W2, W3, Wt1, Wt2, Wt3,
                                                 x, xp, perm, ctrl);

    gemm_k<DIN, HID, 128, 8, 0, false><<<dim3(MAXTILES, 8), 256, 0, stream>>>(
        xp, Wt1, b1, h1, ctrl, tileExpert, tileBase, perm);
    gemm_k<HID, HID, 128, 8, 0, false><<<dim3(MAXTILES, 8), 256, 0, stream>>>(
        h1, Wt2, b2, h2, ctrl, tileExpert, tileBase, perm);
    gemm_k<HID, DOUT, 64, 8, 1, true><<<dim3(MAXTILES, 8), 256, 0, stream>>>(
        h2, Wt3, b3, out, ctrl, tileExpert, tileBase, perm);
}

// Round 19
// 159.701 us; speedup vs baseline: 1.8243x; 1.8243x over previous
//
#include <hip/hip_runtime.h>

// Branch MLP: B=16384 rows, E=4 experts, 512->1024->1024->512, relu/relu/tanh.
// Bucket rows by expert, pad segments to 128-row tiles w/ duplicate rows,
// 3 bf16-MFMA GEMM passes. Weights pre-transposed bf16 [E][N][K]; x
// pre-gathered to permuted bf16 xp. GEMM: R8-proven BM=128, BK=64, 4 waves,
// single-buffer 2-barrier loop, chunk-XOR LDS swizzle + bijective chunked
// XCD swizzle. gemm3 BN=64 (R17). R19: planning split into parallel count_k
// (64 blocks, wave-aggregated atomics) + tiny plan_k — removes the ~10us
// single-block histogram from the critical path.
//
// Workspace (86.1 MB):
//   ctrl[64] | tileExpert[160] | tileBase[160] | perm[16896]
//   Wt1 (4.19MB) | Wt2 (8.39MB) | Wt3 (4.19MB) | h1 (34.6MB) | h2 (34.6MB)
//   xp (17.3MB) aliases h2 (xp dead before gemm2 writes h2).

#define B_N   16384
#define DIN   512
#define HID   1024
#define DOUT  512
#define MAXTILES 136

typedef __attribute__((ext_vector_type(8))) short bf16x8;
typedef __attribute__((ext_vector_type(4))) float f32x4;
typedef __attribute__((address_space(3))) unsigned int lds_u32;
typedef const __attribute__((address_space(1))) unsigned int glb_u32;

__device__ __forceinline__ void gll16(const void* g, void* l) {
    __builtin_amdgcn_global_load_lds((glb_u32*)g, (lds_u32*)l, 16, 0, 0);
}

__device__ __forceinline__ unsigned short f2bf(float f) {
    unsigned int u = __float_as_uint(f);
    u += 0x7FFFu + ((u >> 16) & 1u);   // RNE
    return (unsigned short)(u >> 16);
}

__device__ __forceinline__ float fast_tanh(float x) {
    x = fminf(fmaxf(x, -9.0f), 9.0f);
    float t = __builtin_amdgcn_exp2f(x * 2.8853900817779268f);
    return (t - 1.0f) * __builtin_amdgcn_rcpf(t + 1.0f);
}

// Parallel histogram: 64 blocks, wave-aggregated (4 atomics/wave/expert max).
// ctrl[0..3] must start at 0: plan_k zeroed them last call? No state across
// calls allowed -> zero_k below runs first each call.
__global__ void zero_k(int* __restrict__ ctrl) {
    if (threadIdx.x < 16) ctrl[threadIdx.x] = 0;
}

__global__ void count_k(const int* __restrict__ cmd, int* __restrict__ ctrl) {
    int i = blockIdx.x * 256 + threadIdx.x;
    int e = cmd[i] & 3;
    int lane = threadIdx.x & 63;
#pragma unroll
    for (int ee = 0; ee < 4; ++ee) {
        unsigned long long mask = __ballot(e == ee);
        int leader = __ffsll((unsigned long long)mask) - 1;
        if (mask && lane == leader)
            atomicAdd(&ctrl[ee], __popcll(mask));
    }
}

// Tiny: build tile plan + segment bases + zero scatter cursors.
__global__ void plan_k(int* __restrict__ ctrl, int* __restrict__ tileExpert,
                       int* __restrict__ tileBase) {
    if (threadIdx.x == 0) {
        int P = 0, nt = 0;
        for (int e = 0; e < 4; ++e) {
            ctrl[4 + e] = 0;          // scatter cursors
            ctrl[8 + e] = P;
            int tiles = (ctrl[e] + 127) >> 7;
            for (int t = 0; t < tiles; ++t) {
                tileExpert[nt] = e;
                tileBase[nt] = P + t * 128;
                ++nt;
            }
            P += tiles * 128;
        }
        ctrl[12] = P;                 // total padded rows
        ctrl[13] = nt;                // total tiles
    }
}

// Wave-aggregated scatter: one atomicAdd(popcount) per wave per expert.
__global__ void scatter_k(const int* __restrict__ cmd, int* __restrict__ ctrl,
                          int* __restrict__ perm) {
    int i = blockIdx.x * 256 + threadIdx.x;
    int e = cmd[i] & 3;
    int lane = threadIdx.x & 63;
#pragma unroll
    for (int ee = 0; ee < 4; ++ee) {
        unsigned long long mask = __ballot(e == ee);
        if (e == ee) {
            int leader = __ffsll((unsigned long long)mask) - 1;
            int rank = __popcll(mask & ((1ull << lane) - 1ull));
            int wbase = 0;
            if (lane == leader)
                wbase = atomicAdd(&ctrl[4 + ee], __popcll(mask));
            wbase = __builtin_amdgcn_readfirstlane(wbase);
            perm[ctrl[8 + ee] + wbase + rank] = i;
        }
    }
}

// Fused prep: blocks [0,8192) transpose+convert weights (packed uint writes);
// blocks [8192,12416) gather x -> permuted bf16 xp and fill pad perm entries.
__global__ __launch_bounds__(256) void prep_data_k(
    const float* __restrict__ W1, const float* __restrict__ W2,
    const float* __restrict__ W3, unsigned short* __restrict__ Wt1,
    unsigned short* __restrict__ Wt2, unsigned short* __restrict__ Wt3,
    const float* __restrict__ x, unsigned short* __restrict__ xp,
    int* __restrict__ perm, const int* __restrict__ ctrl)
{
    int b = blockIdx.x;
    if (b < 8192) {
        int e = b >> 11, r = b & 2047;
        const float* W; unsigned short* Wt; int KD, ND, kt, nt;
        if (r < 512)       { W = W1; Wt = Wt1; KD = 512;  ND = 1024; kt = r & 15;           nt = r >> 4; }
        else if (r < 1536) { W = W2; Wt = Wt2; KD = 1024; ND = 1024; kt = (r - 512) & 31;   nt = (r - 512) >> 5; }
        else               { W = W3; Wt = Wt3; KD = 1024; ND = 512;  kt = (r - 1536) & 31;  nt = (r - 1536) >> 5; }
        __shared__ float t[32][33];
        size_t base = (size_t)e * KD * ND;
        int k0 = kt * 32, n0 = nt * 32;
        int tx = threadIdx.x & 31, ty = threadIdx.x >> 5;
#pragma unroll
        for (int s = 0; s < 4; ++s)
            t[ty + s * 8][tx] = W[base + (size_t)(k0 + ty + s * 8) * ND + n0 + tx];
        __syncthreads();
        int tx2 = (threadIdx.x & 15) * 2, ny = threadIdx.x >> 4;
#pragma unroll
        for (int s = 0; s < 2; ++s) {
            int n = ny + s * 16;
            unsigned int v = (unsigned)f2bf(t[tx2][n])
                           | ((unsigned)f2bf(t[tx2 + 1][n]) << 16);
            *(unsigned int*)&Wt[base + (size_t)(n0 + n) * KD + k0 + tx2] = v;
        }
    } else {
        int g = b - 8192;
        int p = g * 4 + (int)(threadIdx.x >> 6);
        if (p >= ctrl[12]) return;
        int lane = threadIdx.x & 63;
        int e = (p >= ctrl[9]) + (p >= ctrl[10]) + (p >= ctrl[11]);
        int segBase = ctrl[8 + e];
        int src;
        if (p < segBase + ctrl[e]) {
            src = perm[p];
        } else {
            src = perm[segBase];              // duplicate a valid same-expert row
            if (lane == 0) perm[p] = src;     // so gemm3 scatter-epilogue is safe
        }
        const float* xr = x + (size_t)src * DIN + lane * 8;
        float4 a = *(const float4*)xr;
        float4 c = *(const float4*)(xr + 4);
        uint4 o;
        o.x = (unsigned)f2bf(a.x) | ((unsigned)f2bf(a.y) << 16);
        o.y = (unsigned)f2bf(a.z) | ((unsigned)f2bf(a.w) << 16);
        o.z = (unsigned)f2bf(c.x) | ((unsigned)f2bf(c.y) << 16);
        o.w = (unsigned)f2bf(c.z) | ((unsigned)f2bf(c.w) << 16);
        *(uint4*)(xp + (size_t)p * DIN + lane * 8) = o;
    }
}

// Grouped GEMM: C = act(A @ Wt[e]^T + b[e]). BM=128, BN template (128 or 64),
// BK=64, 256 thr = 4 waves (2x2 quadrants: wave tile 64 x BN/2). Single
// buffer, 2 barriers per K-step. Chunk-XOR involution: LDS slot s of row r
// holds global 16B-chunk (s ^ (r&7)); ds_read XORs the same. gll16 LDS dest
// stays tid*16B-linear per call. Chunked XCD swizzle: XCD x covers tiles
// [17x,17x+17) x all panels (grid = 136*PN, divisible by 8).
template<int K, int N, int BN, int PN, int ACT, bool SCATTER_OUT>
__global__ __launch_bounds__(256) void gemm_k(
    const unsigned short* __restrict__ A, const unsigned short* __restrict__ Bt,
    const float* __restrict__ bias, void* __restrict__ Outp,
    const int* __restrict__ ctrl, const int* __restrict__ tileExpert,
    const int* __restrict__ tileBase, const int* __restrict__ perm)
{
    constexpr int NI = BN / 32;               // frags per wave along N (4 or 2)
    constexpr int BCALLS = BN / 32;           // B staging calls (32 rows each)
    const int l = (int)blockIdx.x + MAXTILES * (int)blockIdx.y;
    const int swz = (l & 7) * (17 * PN) + (l >> 3);
    const int tile = swz / PN;                // PN pow2 -> shift
    const int panel = swz & (PN - 1);
    if (tile >= ctrl[13]) return;
    const int e = tileExpert[tile];
    const int rowBase = tileBase[tile];
    const int n0 = panel * BN;

    __shared__ unsigned short Als[128 * 64];  // 16 KB
    __shared__ unsigned short Bls[BN * 64];   // 16 or 8 KB

    const int tid = threadIdx.x;
    const int lane = tid & 63;
    const int w = tid >> 6;
    const int wm = w >> 1, wn = w & 1;
    const int lr = lane & 15, lh = lane >> 4;

    f32x4 acc[4][NI] = {};

    // Staging: thread t -> row tr (within 32-row call-block), chunk-slot tc.
    // Source chunk = tc ^ (tr&7)  (row&7 == tr&7 for every call base).
    const int tr = tid >> 3;                  // 0..31
    const int tc = tid & 7;                   // chunk slot 0..7
    const int cs = (tc ^ (tr & 7)) * 8;       // source ushort offset in row
    const unsigned short* As = A + (size_t)(rowBase + tr) * K + cs;
    const unsigned short* Bs = Bt + ((size_t)e * N + n0 + tr) * K + cs;
    const int ldst = tr * 64 + tc * 8;        // ushort idx; byte == tid*16

    constexpr int NK = K / 64;
    for (int kq = 0; kq < NK; ++kq) {
        const int k0 = kq * 64;
        __syncthreads();                      // prior reads of buffer done
#pragma unroll
        for (int j = 0; j < 4; ++j)
            gll16(As + (size_t)(j * 32) * K + k0, &Als[j * 2048 + ldst]);
#pragma unroll
        for (int j = 0; j < BCALLS; ++j)
            gll16(Bs + (size_t)(j * 32) * K + k0, &Bls[j * 2048 + ldst]);
        __syncthreads();                      // drains vmcnt before release
#pragma unroll
        for (int kk = 0; kk < 2; ++kk) {
            const int ksl = ((kk * 4 + lh) ^ (lr & 7)) * 8;   // swizzled read
            bf16x8 afr[4], bfr[NI];
#pragma unroll
            for (int mi = 0; mi < 4; ++mi)
                afr[mi] = *(const bf16x8*)&Als[(wm * 64 + mi * 16 + lr) * 64 + ksl];
#pragma unroll
            for (int ni = 0; ni < NI; ++ni)
                bfr[ni] = *(const bf16x8*)&Bls[(wn * (BN / 2) + ni * 16 + lr) * 64 + ksl];
#pragma unroll
            for (int mi = 0; mi < 4; ++mi)
#pragma unroll
                for (int ni = 0; ni < NI; ++ni)
                    acc[mi][ni] = __builtin_amdgcn_mfma_f32_16x16x32_bf16(
                        afr[mi], bfr[ni], acc[mi][ni], 0, 0, 0);
        }
    }

    float bv[NI];
    int colv[NI];
#pragma unroll
    for (int ni = 0; ni < NI; ++ni) {
        colv[ni] = n0 + wn * (BN / 2) + ni * 16 + lr;
        bv[ni] = bias[e * N + colv[ni]];
    }
#pragma unroll
    for (int mi = 0; mi < 4; ++mi) {
#pragma unroll
        for (int r = 0; r < 4; ++r) {
            int rowL = wm * 64 + mi * 16 + lh * 4 + r;   // C/D: row=(lane>>4)*4+reg
            int gRow = rowBase + rowL;
            int orow = SCATTER_OUT ? perm[gRow] : gRow;
#pragma unroll
            for (int ni = 0; ni < NI; ++ni) {
                float v = acc[mi][ni][r] + bv[ni];
                if (ACT == 0) v = fmaxf(v, 0.0f);
                else          v = fast_tanh(v);
                if (SCATTER_OUT)
                    ((float*)Outp)[(size_t)orow * N + colv[ni]] = v;
                else
                    ((unsigned short*)Outp)[(size_t)orow * N + colv[ni]] = f2bf(v);
            }
        }
    }
}

extern "C" void kernel_launch(void* const* d_in, const int* in_sizes, int n_in,
                              void* d_out, int out_size, void* d_ws, size_t ws_size,
                              hipStream_t stream) {
    const float* x  = (const float*)d_in[0];
    const int*   cmd= (const int*)d_in[1];
    const float* W1 = (const float*)d_in[2];
    const float* b1 = (const float*)d_in[3];
    const float* W2 = (const float*)d_in[4];
    const float* b2 = (const float*)d_in[5];
    const float* W3 = (const float*)d_in[6];
    const float* b3 = (const float*)d_in[7];
    float* out = (float*)d_out;

    char* w = (char*)d_ws;
    int* ctrl       = (int*)w;
    int* tileExpert = ctrl + 64;
    int* tileBase   = ctrl + 224;
    int* perm       = ctrl + 512;                         // 16896 ints
    unsigned short* Wt1 = (unsigned short*)(w + 131072);
    unsigned short* Wt2 = (unsigned short*)(w + 131072 + 4194304);
    unsigned short* Wt3 = (unsigned short*)(w + 131072 + 12582912);
    unsigned short* h1  = (unsigned short*)(w + 131072 + 16777216);
    unsigned short* h2  = h1 + (size_t)16896 * HID;       // 34.6 MB each
    unsigned short* xp  = h2;                             // aliases h2 (WAR-safe)

    zero_k<<<1, 64, 0, stream>>>(ctrl);
    count_k<<<B_N / 256, 256, 0, stream>>>(cmd, ctrl);
    plan_k<<<1, 64, 0, stream>>>(ctrl, tileExpert, tileBase);
    scatter_k<<<B_N / 256, 256, 0, stream>>>(cmd, ctrl, perm);
    prep_data_k<<<8192 + 4224, 256, 0, stream>>>(W1, W2, W3, Wt1, Wt2, Wt3,
                                                 x, xp, perm, ctrl);

    gemm_k<DIN, HID, 128, 8, 0, false><<<dim3(MAXTILES, 8), 256, 0, stream>>>(
        xp, Wt1, b1, h1, ctrl, tileExpert, tileBase, perm);
    gemm_k<HID, HID, 128, 8, 0, false><<<dim3(MAXTILES, 8), 256, 0, stream>>>(
        h1, Wt2, b2, h2, ctrl, tileExpert, tileBase, perm);
    gemm_k<HID, DOUT, 64, 8, 1, true><<<dim3(MAXTILES, 8), 256, 0, stream>>>(
        h2, Wt3, b3, out, ctrl, tileExpert, tileBase, perm);
}